// Round 6
// baseline (242.688 us; speedup 1.0000x reference)
//
#include <hip/hip_runtime.h>
#include <hip/hip_bf16.h>
#include <math.h>

// Problem constants
#define NCLS   19
#define KPC    100
#define NA     1900       // anchors (also first NA contrast cols)
#define NM     20000      // memory rows
#define NC     21900      // contrast rows = NA + NM
#define NCP2   22016      // contrast cols padded to multiple of 128
#define D      256        // feature dim
#define HW     16384      // 128*128
#define NPIX   131072     // 8*128*128
#define NT_M   15         // 1920/128 m-tiles
#define NT_N   172        // 22016/128 n-tiles
#define NTILES (NT_M * NT_N)   // 2580 blocks, 1 tile each

// K1 block partition
#define B_SAMPLE 0        // [0,19)    sampler, class = b
#define B_MEM    19       // [19,2519) memory normalize, 8 rows/block
#define B_CLAB   2519     // [2519,2605) clab stripes (86*256 = 22016 exact)
#define B_PAD    2605     // [2605,2620) bf16 pad-col zero stripes
#define B_ZERO   2620     // zero rowS/rowP
#define K1_GRID  2621

typedef __attribute__((ext_vector_type(8))) short bf16x8;
typedef __attribute__((ext_vector_type(4))) float f32x4;

// workspace byte offsets
#define WS_ROWS  64        // 1920 f
#define WS_ROWP  7744      // 1920 f
#define WS_IDX   15424     // 1900 ints
#define WS_CLAB  30720     // 22016 ints
#define WS_CT2   118784    // bf16 [32 kq][22016 n][8] = 11,272,192 B

__device__ __forceinline__ short f2bf(float x) {
    __hip_bfloat16 h = __float2bfloat16(x);
    return *(short*)&h;
}

// ---------------- K1: independent prep work, partitioned by blockIdx ----------------
__global__ void prep_kernel(const int* __restrict__ labels, const float* __restrict__ mem,
                            const int* __restrict__ memlab,
                            int* __restrict__ idx, int* __restrict__ clab,
                            short* __restrict__ Ct2,
                            float* __restrict__ rowS, float* __restrict__ rowP) {
    const int b = blockIdx.x;
    const int t = threadIdx.x;
    if (b < B_MEM) {
        // ---- first-K-per-class sampler (class = b), ascending order ----
        const int c = b;
        const int wave = t >> 6, lane = t & 63;
        __shared__ int s_base;
        __shared__ int s_wavecnt[4];
        if (t == 0) s_base = 0;
        __syncthreads();
        for (int start = 0; start < NPIX; start += 256) {
            const int i = start + t;
            const bool pred = (labels[i] == c);
            const unsigned long long bm = __ballot(pred);
            if (lane == 0) s_wavecnt[wave] = __popcll(bm);
            __syncthreads();
            const int base = s_base;
            int wbase = 0;
            for (int w = 0; w < wave; ++w) wbase += s_wavecnt[w];
            const int chunk_total = s_wavecnt[0] + s_wavecnt[1] + s_wavecnt[2] + s_wavecnt[3];
            if (pred) {
                const int rank = base + wbase + __popcll(bm & ((1ULL << lane) - 1ULL));
                if (rank < KPC) idx[c * KPC + rank] = i;
            }
            __syncthreads();
            if (t == 0) s_base = base + chunk_total;
            if (base + chunk_total >= KPC) break;
        }
    } else if (b < B_CLAB) {
        // ---- normalize 8 memory rows -> Ct2 cols [NA, NC) ----
        const int r  = (b - B_MEM) * 8 + (t >> 5);
        const int kq = t & 31;
        const float4 v0 = *(const float4*)(mem + (size_t)r * D + kq * 8);
        const float4 v1 = *(const float4*)(mem + (size_t)r * D + kq * 8 + 4);
        float ssq = v0.x*v0.x + v0.y*v0.y + v0.z*v0.z + v0.w*v0.w
                  + v1.x*v1.x + v1.y*v1.y + v1.z*v1.z + v1.w*v1.w;
        #pragma unroll
        for (int o = 16; o; o >>= 1) ssq += __shfl_xor(ssq, o, 32);
        const float inv = 1.0f / fmaxf(sqrtf(ssq), 1e-12f);
        bf16x8 ov;
        ov[0] = f2bf(v0.x * inv); ov[1] = f2bf(v0.y * inv);
        ov[2] = f2bf(v0.z * inv); ov[3] = f2bf(v0.w * inv);
        ov[4] = f2bf(v1.x * inv); ov[5] = f2bf(v1.y * inv);
        ov[6] = f2bf(v1.z * inv); ov[7] = f2bf(v1.w * inv);
        *(bf16x8*)(Ct2 + ((size_t)kq * NCP2 + NA + r) * 8) = ov;
    } else if (b < B_PAD) {
        // ---- contrast labels stripe ----
        const int i = (b - B_CLAB) * 256 + t;     // < 22016 exact
        clab[i] = (i < NA) ? ((i * 5243) >> 19)
                           : ((i < NC) ? memlab[i - NA] : -1);
    } else if (b < B_ZERO) {
        // ---- zero bf16 pad cols (n = 21900..22015) ----
        const int e = (b - B_PAD) * 256 + t;
        if (e < 32 * (NCP2 - NC)) {
            const int kq = e / (NCP2 - NC);
            const int n  = NC + (e - kq * (NCP2 - NC));
            bf16x8 z = {};
            *(bf16x8*)(Ct2 + ((size_t)kq * NCP2 + n) * 8) = z;
        }
    } else {
        // ---- zero accumulators ----
        for (int i = t; i < 1920; i += 256) { rowS[i] = 0.f; rowP[i] = 0.f; }
    }
}

// ---------------- K2: gather + normalize anchors -> Ct2 cols [0, NA) ----------------
__global__ void anchor_kernel(const float* __restrict__ pixel, const int* __restrict__ idx,
                              short* __restrict__ Ct2) {
    const int t = threadIdx.x;
    const int a = blockIdx.x * 8 + (t >> 5);
    const int kq = t & 31;
    if (a >= NA) return;
    const int p = idx[a];
    const int bi = p >> 14;
    const int hw = p & (HW - 1);
    const float* base = pixel + ((size_t)(bi * D + kq * 8)) * HW + hw;
    float v[8];
    float ssq = 0.f;
    #pragma unroll
    for (int j = 0; j < 8; ++j) { v[j] = base[(size_t)j * HW]; ssq += v[j] * v[j]; }
    #pragma unroll
    for (int o = 16; o; o >>= 1) ssq += __shfl_xor(ssq, o, 32);
    const float inv = 1.0f / fmaxf(sqrtf(ssq), 1e-12f);
    bf16x8 ov;
    #pragma unroll
    for (int j = 0; j < 8; ++j) ov[j] = f2bf(v[j] * inv);
    *(bf16x8*)(Ct2 + ((size_t)kq * NCP2 + a) * 8) = ov;
}

// ---------------- K3: direct-to-register MFMA GEMM (no LDS staging, no barriers) ----------------
// 128x128 tile, 4 waves in 2x2, each wave 64x64 via 4x4 grid of 16x16x32 bf16 MFMA.
// MFMA fragments are read STRAIGHT from Ct2's [kq][n][8] layout: 64 lanes x 16B =
// four contiguous 256B segments per load. No LDS tiles -> zero K-loop barriers ->
// the compiler software-pipelines loads under MFMAs with counted vmcnt, and
// 4 blocks/CU (LDS~0) provide TLP. Costs 2x L2 traffic (660 MB @ 34.5 TB/s = 19 us
// floor) vs staged, but removes the 8 full-drain epochs that dominated at 120+ us.
// SWAPPED operands: mfma(bfr, af, acc) -> output col(l16)=m, row(quad*4+reg)=n,
// so the sum-over-n epilogue is lane-local (16 vals) + 2 quad shuffles.
__global__ __launch_bounds__(256, 4)
void mfma_gemm_kernel(const short* __restrict__ Ct2, const int* __restrict__ clab,
                      float* __restrict__ rowS, float* __restrict__ rowP) {
    __shared__ int s_nlab[128];
    const int tid  = threadIdx.x;
    const int lane = tid & 63;
    const int w    = tid >> 6;           // wave 0..3
    const int wm   = w >> 1, wn = w & 1;
    const int quad = lane >> 4;
    const int l16  = lane & 15;

    // bijective chunked XCD swizzle: 2580 = 8*322 + 4  (q=322, r=4)
    const int bid = blockIdx.x;
    const int x   = bid & 7;             // dispatch round-robins XCDs on flat id
    const int j   = bid >> 3;
    const int wg  = (x < 4 ? x * 323 : 1292 + (x - 4) * 322) + j;
    const int m0  = (wg % NT_M) * 128;
    const int n0  = (wg / NT_M) * 128;

    if (tid < 128) s_nlab[tid] = clab[n0 + tid];

    const int aCol = m0 + wm * 64 + l16;     // + mi*16
    const int bCol = n0 + wn * 64 + l16;     // + ni*16

    f32x4 acc[4][4] = {};                // [ni][mi]  (swapped output)

    #pragma unroll
    for (int kb = 0; kb < 8; ++kb) {
        const int kqb = kb * 4 + quad;   // k-row 0..31 (K=32 per MFMA = 4 kq chunks)
        const short* kbase = Ct2 + (size_t)kqb * NCP2 * 8;
        bf16x8 af[4], bfr[4];
        #pragma unroll
        for (int mi = 0; mi < 4; ++mi)
            af[mi] = *(const bf16x8*)(kbase + (size_t)(aCol + mi * 16) * 8);
        #pragma unroll
        for (int ni = 0; ni < 4; ++ni)
            bfr[ni] = *(const bf16x8*)(kbase + (size_t)(bCol + ni * 16) * 8);
        #pragma unroll
        for (int ni = 0; ni < 4; ++ni)
            #pragma unroll
            for (int mi = 0; mi < 4; ++mi)
                acc[ni][mi] = __builtin_amdgcn_mfma_f32_16x16x32_bf16(
                    bfr[ni], af[mi], acc[ni][mi], 0, 0, 0);   // SWAPPED
    }

    __syncthreads();                     // s_nlab visible

    // epilogue: per-lane m column, sum over this lane's 16 n values in-register
    const int m_base = m0 + wm * 64 + l16;
    #pragma unroll
    for (int mi = 0; mi < 4; ++mi) {
        const int m    = m_base + mi * 16;
        const int mlab = (m * 5243) >> 19;                 // m/100 (>=19 for pad rows: no match)
        float s = 0.f, p = 0.f;
        #pragma unroll
        for (int ni = 0; ni < 4; ++ni) {
            const int nb = wn * 64 + ni * 16 + quad * 4;   // tile-local n base for this lane
            const int4 lb = *(const int4*)&s_nlab[nb];
            #pragma unroll
            for (int r = 0; r < 4; ++r) {
                const int n  = n0 + nb + r;
                const int nl = (&lb.x)[r];
                if (n < NC && n != m) {
                    const float l = acc[ni][mi][r] * 10.0f;
                    s += __expf(l);
                    if (nl == mlab) p += l;
                }
            }
        }
        // finish sum over n: combine the 4 quads (lanes l16, 16+l16, 32+l16, 48+l16)
        s += __shfl_xor(s, 16, 64); s += __shfl_xor(s, 32, 64);
        p += __shfl_xor(p, 16, 64); p += __shfl_xor(p, 32, 64);
        if (quad == 0 && m < NA) {
            atomicAdd(&rowS[m], s);
            atomicAdd(&rowP[m], p);
        }
    }
}

// ---------------- K4: final loss (cnt from memlab histogram) ----------------
__global__ void finalize_kernel(const float* __restrict__ rowS, const float* __restrict__ rowP,
                                const int* __restrict__ memlab, float* __restrict__ out) {
    const int t = threadIdx.x;
    __shared__ int hist[NCLS];
    __shared__ float rs[4], rn[4];
    if (t < NCLS) hist[t] = 0;
    __syncthreads();
    for (int i = t; i < NM; i += 256) atomicAdd(&hist[memlab[i]], 1);
    __syncthreads();
    float sum = 0.f, nval = 0.f;
    for (int n = t; n < NA; n += 256) {
        const float cnt  = (float)(KPC - 1 + hist[(n * 5243) >> 19]);
        const float logS = logf(rowS[n] + 1e-12f);
        const float mean = (rowP[n] - cnt * logS) / fmaxf(cnt, 1.0f);
        if (cnt > 0.f) { sum += mean; nval += 1.f; }
    }
    for (int o = 32; o; o >>= 1) {
        sum  += __shfl_xor(sum, o, 64);
        nval += __shfl_xor(nval, o, 64);
    }
    if ((t & 63) == 0) { rs[t >> 6] = sum; rn[t >> 6] = nval; }
    __syncthreads();
    if (t == 0) {
        const float s  = rs[0] + rs[1] + rs[2] + rs[3];
        const float nv = rn[0] + rn[1] + rn[2] + rn[3];
        out[0] = -(0.1f / 0.07f) * (s / fmaxf(nv, 1.f));
    }
}

extern "C" void kernel_launch(void* const* d_in, const int* in_sizes, int n_in,
                              void* d_out, int out_size, void* d_ws, size_t ws_size,
                              hipStream_t stream) {
    const float* pixel  = (const float*)d_in[0];   // [8,256,128,128]
    const int*   labels = (const int*)d_in[1];     // [8,128,128]
    const float* mem    = (const float*)d_in[2];   // [20000,256]
    const int*   memlab = (const int*)d_in[3];     // [20000]
    char* ws = (char*)d_ws;
    float* rowS = (float*)(ws + WS_ROWS);
    float* rowP = (float*)(ws + WS_ROWP);
    int*   idx  = (int*)(ws + WS_IDX);
    int*   clab = (int*)(ws + WS_CLAB);
    short* Ct2  = (short*)(ws + WS_CT2);
    float* out  = (float*)d_out;

    prep_kernel<<<dim3(K1_GRID), dim3(256), 0, stream>>>(
        labels, mem, memlab, idx, clab, Ct2, rowS, rowP);
    anchor_kernel<<<dim3(238), dim3(256), 0, stream>>>(pixel, idx, Ct2);
    mfma_gemm_kernel<<<dim3(NTILES), dim3(256), 0, stream>>>(Ct2, clab, rowS, rowP);
    finalize_kernel<<<dim3(1), dim3(256), 0, stream>>>(rowS, rowP, memlab, out);
}

// Round 7
// 230.404 us; speedup vs baseline: 1.0533x; 1.0533x over previous
//
#include <hip/hip_runtime.h>
#include <hip/hip_bf16.h>
#include <math.h>

// Problem constants
#define NCLS   19
#define KPC    100
#define NA     1900       // anchors (also first NA contrast cols)
#define NM     20000      // memory rows
#define NC     21900      // contrast rows = NA + NM
#define NCP2   22016      // contrast cols padded to multiple of 128
#define D      256        // feature dim
#define HW     16384      // 128*128
#define NPIX   131072     // 8*128*128
#define NT_M   15         // 1920/128 m-tiles
#define NT_N   172        // 22016/128 n-tiles
#define NTILES (NT_M * NT_N)   // 2580 blocks, 1 tile each

// K1 block partition (all sections fully independent - no intra-kernel deps)
#define ABPC    13        // anchor blocks per class (13*8 = 104 >= 100 ranks)
#define B_ANCH  0         // [0,247)      anchor scan+gather, 8 anchors/block
#define B_MEM   247       // [247,2747)   memory normalize, 8 rows/block
#define B_CLAB  2747      // [2747,2833)  clab stripes (86*256 = 22016 exact)
#define B_PAD   2833      // [2833,2848)  bf16 pad-col zero stripes
#define B_ZERO  2848      // zero rowS/rowP
#define K1_GRID 2849

typedef __attribute__((ext_vector_type(8))) short bf16x8;
typedef __attribute__((ext_vector_type(4))) float f32x4;

// workspace byte offsets
#define WS_ROWS  64        // 1920 f
#define WS_ROWP  7744      // 1920 f
#define WS_CLAB  30720     // 22016 ints
#define WS_CT2   118784    // bf16 [32 kq][22016 n][8] = 11,272,192 B

__device__ __forceinline__ short f2bf(float x) {
    __hip_bfloat16 h = __float2bfloat16(x);
    return *(short*)&h;
}

// ---------------- K1: ALL prep work, every block independent ----------------
// Anchor blocks self-compute their sample indices from labels (idx[] is a pure
// function of labels: rank-r occurrence of class c), removing the sampler kernel
// and the sampler->gather launch dependency entirely.
__global__ void prep_kernel(const float* __restrict__ pixel, const int* __restrict__ labels,
                            const float* __restrict__ mem, const int* __restrict__ memlab,
                            int* __restrict__ clab, short* __restrict__ Ct2,
                            float* __restrict__ rowS, float* __restrict__ rowP) {
    const int b = blockIdx.x;
    const int t = threadIdx.x;
    if (b < B_MEM) {
        // ---- scan labels for ranks [r0, rmax) of class c, then gather+normalize ----
        const int c    = b / ABPC;
        const int r0   = (b % ABPC) * 8;
        const int rmax = (r0 + 8 < KPC) ? r0 + 8 : KPC;    // last block: 4 anchors
        const int wave = t >> 6, lane = t & 63;
        __shared__ int s_idx[8];
        __shared__ int s_base;
        __shared__ int s_wavecnt[4];
        if (t == 0) s_base = 0;
        __syncthreads();
        for (int start = 0; start < NPIX; start += 256) {
            const int i = start + t;
            const bool pred = (labels[i] == c);
            const unsigned long long bm = __ballot(pred);
            if (lane == 0) s_wavecnt[wave] = __popcll(bm);
            __syncthreads();
            const int base = s_base;
            int wbase = 0;
            for (int w = 0; w < wave; ++w) wbase += s_wavecnt[w];
            const int chunk_total = s_wavecnt[0] + s_wavecnt[1] + s_wavecnt[2] + s_wavecnt[3];
            if (pred) {
                const int rank = base + wbase + __popcll(bm & ((1ULL << lane) - 1ULL));
                if (rank >= r0 && rank < rmax) s_idx[rank - r0] = i;
            }
            __syncthreads();
            if (t == 0) s_base = base + chunk_total;
            if (base + chunk_total >= rmax) break;
        }
        __syncthreads();
        // gather + normalize: 8 anchors x 32 lanes (one 8-d chunk each)
        const int ai = t >> 5;                 // 0..7
        const int kq = t & 31;
        const int r  = r0 + ai;
        if (r < rmax) {
            const int a   = c * KPC + r;       // anchor / Ct2 column
            const int pix = s_idx[ai];
            const int bi  = pix >> 14;
            const int hw  = pix & (HW - 1);
            const float* base = pixel + ((size_t)(bi * D + kq * 8)) * HW + hw;
            float v[8];
            float ssq = 0.f;
            #pragma unroll
            for (int j = 0; j < 8; ++j) { v[j] = base[(size_t)j * HW]; ssq += v[j] * v[j]; }
            #pragma unroll
            for (int o = 16; o; o >>= 1) ssq += __shfl_xor(ssq, o, 32);
            const float inv = 1.0f / fmaxf(sqrtf(ssq), 1e-12f);
            bf16x8 ov;
            #pragma unroll
            for (int j = 0; j < 8; ++j) ov[j] = f2bf(v[j] * inv);
            *(bf16x8*)(Ct2 + ((size_t)kq * NCP2 + a) * 8) = ov;
        }
    } else if (b < B_CLAB) {
        // ---- normalize 8 memory rows -> Ct2 cols [NA, NC) ----
        const int r  = (b - B_MEM) * 8 + (t >> 5);
        const int kq = t & 31;
        const float4 v0 = *(const float4*)(mem + (size_t)r * D + kq * 8);
        const float4 v1 = *(const float4*)(mem + (size_t)r * D + kq * 8 + 4);
        float ssq = v0.x*v0.x + v0.y*v0.y + v0.z*v0.z + v0.w*v0.w
                  + v1.x*v1.x + v1.y*v1.y + v1.z*v1.z + v1.w*v1.w;
        #pragma unroll
        for (int o = 16; o; o >>= 1) ssq += __shfl_xor(ssq, o, 32);
        const float inv = 1.0f / fmaxf(sqrtf(ssq), 1e-12f);
        bf16x8 ov;
        ov[0] = f2bf(v0.x * inv); ov[1] = f2bf(v0.y * inv);
        ov[2] = f2bf(v0.z * inv); ov[3] = f2bf(v0.w * inv);
        ov[4] = f2bf(v1.x * inv); ov[5] = f2bf(v1.y * inv);
        ov[6] = f2bf(v1.z * inv); ov[7] = f2bf(v1.w * inv);
        *(bf16x8*)(Ct2 + ((size_t)kq * NCP2 + NA + r) * 8) = ov;
    } else if (b < B_PAD) {
        // ---- contrast labels stripe ----
        const int i = (b - B_CLAB) * 256 + t;     // < 22016 exact
        clab[i] = (i < NA) ? ((i * 5243) >> 19)
                           : ((i < NC) ? memlab[i - NA] : -1);
    } else if (b < B_ZERO) {
        // ---- zero bf16 pad cols (n = 21900..22015) ----
        const int e = (b - B_PAD) * 256 + t;
        if (e < 32 * (NCP2 - NC)) {
            const int kq = e / (NCP2 - NC);
            const int n  = NC + (e - kq * (NCP2 - NC));
            bf16x8 z = {};
            *(bf16x8*)(Ct2 + ((size_t)kq * NCP2 + n) * 8) = z;
        }
    } else {
        // ---- zero accumulators ----
        for (int i = t; i < 1920; i += 256) { rowS[i] = 0.f; rowP[i] = 0.f; }
    }
}

// ---------------- K2: direct-to-register MFMA GEMM (no LDS staging, no barriers) ----------------
// 128x128 tile, 4 waves in 2x2, each wave 64x64 via 4x4 grid of 16x16x32 bf16 MFMA.
// Fragments read STRAIGHT from Ct2's [kq][n][8] layout (64 lanes x 16B = four 256B
// segments per load); compiler software-pipelines loads under MFMAs, 4 blocks/CU TLP.
// SWAPPED operands: mfma(bfr, af, acc) -> output col(l16)=m, row(quad*4+reg)=n,
// so the sum-over-n epilogue is lane-local (16 vals) + 2 quad shuffles.
__global__ __launch_bounds__(256, 4)
void mfma_gemm_kernel(const short* __restrict__ Ct2, const int* __restrict__ clab,
                      float* __restrict__ rowS, float* __restrict__ rowP) {
    __shared__ int s_nlab[128];
    const int tid  = threadIdx.x;
    const int lane = tid & 63;
    const int w    = tid >> 6;           // wave 0..3
    const int wm   = w >> 1, wn = w & 1;
    const int quad = lane >> 4;
    const int l16  = lane & 15;

    // bijective chunked XCD swizzle: 2580 = 8*322 + 4  (q=322, r=4)
    const int bid = blockIdx.x;
    const int x   = bid & 7;             // dispatch round-robins XCDs on flat id
    const int j   = bid >> 3;
    const int wg  = (x < 4 ? x * 323 : 1292 + (x - 4) * 322) + j;
    const int m0  = (wg % NT_M) * 128;
    const int n0  = (wg / NT_M) * 128;

    if (tid < 128) s_nlab[tid] = clab[n0 + tid];

    const int aCol = m0 + wm * 64 + l16;     // + mi*16
    const int bCol = n0 + wn * 64 + l16;     // + ni*16

    f32x4 acc[4][4] = {};                // [ni][mi]  (swapped output)

    #pragma unroll
    for (int kb = 0; kb < 8; ++kb) {
        const int kqb = kb * 4 + quad;   // k-row 0..31 (K=32 per MFMA = 4 kq chunks)
        const short* kbase = Ct2 + (size_t)kqb * NCP2 * 8;
        bf16x8 af[4], bfr[4];
        #pragma unroll
        for (int mi = 0; mi < 4; ++mi)
            af[mi] = *(const bf16x8*)(kbase + (size_t)(aCol + mi * 16) * 8);
        #pragma unroll
        for (int ni = 0; ni < 4; ++ni)
            bfr[ni] = *(const bf16x8*)(kbase + (size_t)(bCol + ni * 16) * 8);
        #pragma unroll
        for (int ni = 0; ni < 4; ++ni)
            #pragma unroll
            for (int mi = 0; mi < 4; ++mi)
                acc[ni][mi] = __builtin_amdgcn_mfma_f32_16x16x32_bf16(
                    bfr[ni], af[mi], acc[ni][mi], 0, 0, 0);   // SWAPPED
    }

    __syncthreads();                     // s_nlab visible

    // epilogue: per-lane m column, sum over this lane's 16 n values in-register
    const int m_base = m0 + wm * 64 + l16;
    #pragma unroll
    for (int mi = 0; mi < 4; ++mi) {
        const int m    = m_base + mi * 16;
        const int mlab = (m * 5243) >> 19;                 // m/100 (>=19 for pad rows: no match)
        float s = 0.f, p = 0.f;
        #pragma unroll
        for (int ni = 0; ni < 4; ++ni) {
            const int nb = wn * 64 + ni * 16 + quad * 4;   // tile-local n base for this lane
            const int4 lb = *(const int4*)&s_nlab[nb];
            #pragma unroll
            for (int r = 0; r < 4; ++r) {
                const int n  = n0 + nb + r;
                const int nl = (&lb.x)[r];
                if (n < NC && n != m) {
                    const float l = acc[ni][mi][r] * 10.0f;
                    s += __expf(l);
                    if (nl == mlab) p += l;
                }
            }
        }
        // finish sum over n: combine the 4 quads (lanes l16, 16+l16, 32+l16, 48+l16)
        s += __shfl_xor(s, 16, 64); s += __shfl_xor(s, 32, 64);
        p += __shfl_xor(p, 16, 64); p += __shfl_xor(p, 32, 64);
        if (quad == 0 && m < NA) {
            atomicAdd(&rowS[m], s);
            atomicAdd(&rowP[m], p);
        }
    }
}

// ---------------- K3: final loss (cnt from memlab histogram, int4 scan) ----------------
__global__ void finalize_kernel(const float* __restrict__ rowS, const float* __restrict__ rowP,
                                const int* __restrict__ memlab, float* __restrict__ out) {
    const int t = threadIdx.x;
    __shared__ int hist[NCLS];
    __shared__ float rs[4], rn[4];
    if (t < NCLS) hist[t] = 0;
    __syncthreads();
    for (int i4 = t; i4 < NM / 4; i4 += 256) {     // 5000 int4s, 20 iterations
        const int4 v = ((const int4*)memlab)[i4];
        atomicAdd(&hist[v.x], 1);
        atomicAdd(&hist[v.y], 1);
        atomicAdd(&hist[v.z], 1);
        atomicAdd(&hist[v.w], 1);
    }
    __syncthreads();
    float sum = 0.f, nval = 0.f;
    for (int n = t; n < NA; n += 256) {
        const float cnt  = (float)(KPC - 1 + hist[(n * 5243) >> 19]);
        const float logS = logf(rowS[n] + 1e-12f);
        const float mean = (rowP[n] - cnt * logS) / fmaxf(cnt, 1.0f);
        if (cnt > 0.f) { sum += mean; nval += 1.f; }
    }
    for (int o = 32; o; o >>= 1) {
        sum  += __shfl_xor(sum, o, 64);
        nval += __shfl_xor(nval, o, 64);
    }
    if ((t & 63) == 0) { rs[t >> 6] = sum; rn[t >> 6] = nval; }
    __syncthreads();
    if (t == 0) {
        const float s  = rs[0] + rs[1] + rs[2] + rs[3];
        const float nv = rn[0] + rn[1] + rn[2] + rn[3];
        out[0] = -(0.1f / 0.07f) * (s / fmaxf(nv, 1.f));
    }
}

extern "C" void kernel_launch(void* const* d_in, const int* in_sizes, int n_in,
                              void* d_out, int out_size, void* d_ws, size_t ws_size,
                              hipStream_t stream) {
    const float* pixel  = (const float*)d_in[0];   // [8,256,128,128]
    const int*   labels = (const int*)d_in[1];     // [8,128,128]
    const float* mem    = (const float*)d_in[2];   // [20000,256]
    const int*   memlab = (const int*)d_in[3];     // [20000]
    char* ws = (char*)d_ws;
    float* rowS = (float*)(ws + WS_ROWS);
    float* rowP = (float*)(ws + WS_ROWP);
    int*   clab = (int*)(ws + WS_CLAB);
    short* Ct2  = (short*)(ws + WS_CT2);
    float* out  = (float*)d_out;

    prep_kernel<<<dim3(K1_GRID), dim3(256), 0, stream>>>(
        pixel, labels, mem, memlab, clab, Ct2, rowS, rowP);
    mfma_gemm_kernel<<<dim3(NTILES), dim3(256), 0, stream>>>(Ct2, clab, rowS, rowP);
    finalize_kernel<<<dim3(1), dim3(256), 0, stream>>>(rowS, rowP, memlab, out);
}

// Round 8
// 224.614 us; speedup vs baseline: 1.0805x; 1.0258x over previous
//
#include <hip/hip_runtime.h>
#include <hip/hip_bf16.h>
#include <math.h>

// Problem constants
#define NCLS   19
#define KPC    100
#define NA     1900       // anchors (also first NA contrast cols)
#define NM     20000      // memory rows
#define NC     21900      // contrast rows = NA + NM
#define NCP2   22016      // contrast cols padded to multiple of 128
#define D      256        // feature dim
#define HW     16384      // 128*128
#define NPIX   131072     // 8*128*128
#define NT_M   15         // 1920/128 m-tiles
#define NT_N   172        // 22016/128 n-tiles
#define NTILES (NT_M * NT_N)   // 2580 blocks, 1 tile each

// K1 block partition (all sections fully independent - no intra-kernel deps)
#define ABPC    13        // anchor blocks per class (13*8 = 104 >= 100 ranks)
#define B_ANCH  0         // [0,247)      anchor scan+gather, 8 anchors/block
#define B_MEM   247       // [247,2747)   memory normalize, 8 rows/block
#define B_CLAB  2747      // [2747,2833)  clab stripes (86*256 = 22016 exact)
#define B_PAD   2833      // [2833,2848)  bf16 pad-col zero stripes
#define B_ZERO  2848      // zero rowS/rowP
#define K1_GRID 2849

typedef __attribute__((ext_vector_type(8))) short bf16x8;
typedef __attribute__((ext_vector_type(4))) float f32x4;

// workspace byte offsets
#define WS_ROWS  64        // 1920 f
#define WS_ROWP  7744      // 1920 f
#define WS_CLAB  30720     // 22016 ints
#define WS_CT2   118784    // bf16 [32 kq][22016 n][8] = 11,272,192 B

__device__ __forceinline__ short f2bf(float x) {
    __hip_bfloat16 h = __float2bfloat16(x);
    return *(short*)&h;
}

// ---------------- K1: ALL prep work, every block independent ----------------
__global__ void prep_kernel(const float* __restrict__ pixel, const int* __restrict__ labels,
                            const float* __restrict__ mem, const int* __restrict__ memlab,
                            int* __restrict__ clab, short* __restrict__ Ct2,
                            float* __restrict__ rowS, float* __restrict__ rowP) {
    const int b = blockIdx.x;
    const int t = threadIdx.x;
    if (b < B_MEM) {
        // ---- scan labels for ranks [r0, rmax) of class c, then gather+normalize ----
        const int c    = b / ABPC;
        const int r0   = (b % ABPC) * 8;
        const int rmax = (r0 + 8 < KPC) ? r0 + 8 : KPC;    // last block: 4 anchors
        const int wave = t >> 6, lane = t & 63;
        __shared__ int s_idx[8];
        __shared__ int s_base;
        __shared__ int s_wavecnt[4];
        if (t == 0) s_base = 0;
        __syncthreads();
        for (int start = 0; start < NPIX; start += 256) {
            const int i = start + t;
            const bool pred = (labels[i] == c);
            const unsigned long long bm = __ballot(pred);
            if (lane == 0) s_wavecnt[wave] = __popcll(bm);
            __syncthreads();
            const int base = s_base;
            int wbase = 0;
            for (int w = 0; w < wave; ++w) wbase += s_wavecnt[w];
            const int chunk_total = s_wavecnt[0] + s_wavecnt[1] + s_wavecnt[2] + s_wavecnt[3];
            if (pred) {
                const int rank = base + wbase + __popcll(bm & ((1ULL << lane) - 1ULL));
                if (rank >= r0 && rank < rmax) s_idx[rank - r0] = i;
            }
            __syncthreads();
            if (t == 0) s_base = base + chunk_total;
            if (base + chunk_total >= rmax) break;
        }
        __syncthreads();
        // gather + normalize: 8 anchors x 32 lanes (one 8-d chunk each)
        const int ai = t >> 5;                 // 0..7
        const int kq = t & 31;
        const int r  = r0 + ai;
        if (r < rmax) {
            const int a   = c * KPC + r;       // anchor / Ct2 column
            const int pix = s_idx[ai];
            const int bi  = pix >> 14;
            const int hw  = pix & (HW - 1);
            const float* base = pixel + ((size_t)(bi * D + kq * 8)) * HW + hw;
            float v[8];
            float ssq = 0.f;
            #pragma unroll
            for (int j = 0; j < 8; ++j) { v[j] = base[(size_t)j * HW]; ssq += v[j] * v[j]; }
            #pragma unroll
            for (int o = 16; o; o >>= 1) ssq += __shfl_xor(ssq, o, 32);
            const float inv = 1.0f / fmaxf(sqrtf(ssq), 1e-12f);
            bf16x8 ov;
            #pragma unroll
            for (int j = 0; j < 8; ++j) ov[j] = f2bf(v[j] * inv);
            *(bf16x8*)(Ct2 + ((size_t)kq * NCP2 + a) * 8) = ov;
        }
    } else if (b < B_CLAB) {
        // ---- normalize 8 memory rows -> Ct2 cols [NA, NC) ----
        const int r  = (b - B_MEM) * 8 + (t >> 5);
        const int kq = t & 31;
        const float4 v0 = *(const float4*)(mem + (size_t)r * D + kq * 8);
        const float4 v1 = *(const float4*)(mem + (size_t)r * D + kq * 8 + 4);
        float ssq = v0.x*v0.x + v0.y*v0.y + v0.z*v0.z + v0.w*v0.w
                  + v1.x*v1.x + v1.y*v1.y + v1.z*v1.z + v1.w*v1.w;
        #pragma unroll
        for (int o = 16; o; o >>= 1) ssq += __shfl_xor(ssq, o, 32);
        const float inv = 1.0f / fmaxf(sqrtf(ssq), 1e-12f);
        bf16x8 ov;
        ov[0] = f2bf(v0.x * inv); ov[1] = f2bf(v0.y * inv);
        ov[2] = f2bf(v0.z * inv); ov[3] = f2bf(v0.w * inv);
        ov[4] = f2bf(v1.x * inv); ov[5] = f2bf(v1.y * inv);
        ov[6] = f2bf(v1.z * inv); ov[7] = f2bf(v1.w * inv);
        *(bf16x8*)(Ct2 + ((size_t)kq * NCP2 + NA + r) * 8) = ov;
    } else if (b < B_PAD) {
        // ---- contrast labels stripe ----
        const int i = (b - B_CLAB) * 256 + t;     // < 22016 exact
        clab[i] = (i < NA) ? ((i * 5243) >> 19)
                           : ((i < NC) ? memlab[i - NA] : -1);
    } else if (b < B_ZERO) {
        // ---- zero bf16 pad cols (n = 21900..22015) ----
        const int e = (b - B_PAD) * 256 + t;
        if (e < 32 * (NCP2 - NC)) {
            const int kq = e / (NCP2 - NC);
            const int n  = NC + (e - kq * (NCP2 - NC));
            bf16x8 z = {};
            *(bf16x8*)(Ct2 + ((size_t)kq * NCP2 + n) * 8) = z;
        }
    } else {
        // ---- zero accumulators ----
        for (int i = t; i < 1920; i += 256) { rowS[i] = 0.f; rowP[i] = 0.f; }
    }
}

// ---------------- K2: LDS-staged MFMA GEMM + swapped in-register epilogue ----------------
// 128x128 tile, 4 waves in 2x2, each wave 64x64 via 4x4 grid of 16x16x32 bf16 MFMA.
// LDS staging (global_load_lds, R3-verified loop) halves L1 traffic vs direct-load:
// each Ct2 line enters the CU once, then LDS (128 B/cyc, 2x L1) serves the 2x wave
// redundancy. SWAPPED operands: mfma(bfr, af, acc) -> col(l16)=m, row(quad*4+reg)=n,
// so the sum-over-n epilogue is lane-local (16 vals) + 2 quad shuffles (R6-verified).
__global__ __launch_bounds__(256, 3)
void mfma_gemm_kernel(const short* __restrict__ Ct2, const int* __restrict__ clab,
                      float* __restrict__ rowS, float* __restrict__ rowP) {
    __shared__ __align__(16) short As[8 * 128 * 8];   // 16 KB
    __shared__ __align__(16) short Bs[8 * 128 * 8];   // 16 KB
    __shared__ int s_nlab[128];
    const int tid  = threadIdx.x;
    const int lane = tid & 63;
    const int w    = tid >> 6;           // wave 0..3
    const int wm   = w >> 1, wn = w & 1;
    const int quad = lane >> 4;
    const int l16  = lane & 15;

    // bijective chunked XCD swizzle: 2580 = 8*322 + 4  (q=322, r=4)
    const int bid = blockIdx.x;
    const int x   = bid & 7;             // dispatch round-robins XCDs on flat id
    const int j   = bid >> 3;
    const int wg  = (x < 4 ? x * 323 : 1292 + (x - 4) * 322) + j;
    const int m0  = (wg % NT_M) * 128;
    const int n0  = (wg / NT_M) * 128;

    if (tid < 128) s_nlab[tid] = clab[n0 + tid];

    f32x4 acc[4][4] = {};                // [ni][mi]  (swapped output)

    for (int kc = 0; kc < 4; ++kc) {
        #pragma unroll
        for (int i = 0; i < 4; ++i) {
            const int bl = (w * 4 + i) * 64;   // wave-uniform LDS base
            const int kq = bl >> 7;            // 0..7
            const int ml = bl & 127;           // 0 or 64
            const size_t gA = ((size_t)(kc * 8 + kq) * NCP2 + m0 + ml + lane) * 8;
            __builtin_amdgcn_global_load_lds(
                (const __attribute__((address_space(1))) void*)(Ct2 + gA),
                (__attribute__((address_space(3))) void*)(As + (size_t)bl * 8 + lane * 8),
                16, 0, 0);
            const size_t gB = ((size_t)(kc * 8 + kq) * NCP2 + n0 + ml + lane) * 8;
            __builtin_amdgcn_global_load_lds(
                (const __attribute__((address_space(1))) void*)(Ct2 + gB),
                (__attribute__((address_space(3))) void*)(Bs + (size_t)bl * 8 + lane * 8),
                16, 0, 0);
        }
        __syncthreads();
        #pragma unroll
        for (int ks = 0; ks < 2; ++ks) {
            const int kqb = ks * 4 + quad;
            bf16x8 af[4], bfr[4];
            #pragma unroll
            for (int mi = 0; mi < 4; ++mi)
                af[mi] = *(const bf16x8*)(As + ((kqb * 128) + wm * 64 + mi * 16 + l16) * 8);
            #pragma unroll
            for (int ni = 0; ni < 4; ++ni)
                bfr[ni] = *(const bf16x8*)(Bs + ((kqb * 128) + wn * 64 + ni * 16 + l16) * 8);
            #pragma unroll
            for (int ni = 0; ni < 4; ++ni)
                #pragma unroll
                for (int mi = 0; mi < 4; ++mi)
                    acc[ni][mi] = __builtin_amdgcn_mfma_f32_16x16x32_bf16(
                        bfr[ni], af[mi], acc[ni][mi], 0, 0, 0);   // SWAPPED
        }
        __syncthreads();
    }

    // epilogue: per-lane m column, sum over this lane's 16 n values in-register
    const int m_base = m0 + wm * 64 + l16;
    #pragma unroll
    for (int mi = 0; mi < 4; ++mi) {
        const int m    = m_base + mi * 16;
        const int mlab = (m * 5243) >> 19;                 // m/100 (>=19 for pad rows: no match)
        float s = 0.f, p = 0.f;
        #pragma unroll
        for (int ni = 0; ni < 4; ++ni) {
            const int nb = wn * 64 + ni * 16 + quad * 4;   // tile-local n base for this lane
            const int4 lb = *(const int4*)&s_nlab[nb];
            #pragma unroll
            for (int r = 0; r < 4; ++r) {
                const int n  = n0 + nb + r;
                const int nl = (&lb.x)[r];
                if (n < NC && n != m) {
                    const float l = acc[ni][mi][r] * 10.0f;
                    s += __expf(l);
                    if (nl == mlab) p += l;
                }
            }
        }
        // finish sum over n: combine the 4 quads (lanes l16, 16+l16, 32+l16, 48+l16)
        s += __shfl_xor(s, 16, 64); s += __shfl_xor(s, 32, 64);
        p += __shfl_xor(p, 16, 64); p += __shfl_xor(p, 32, 64);
        if (quad == 0 && m < NA) {
            atomicAdd(&rowS[m], s);
            atomicAdd(&rowP[m], p);
        }
    }
}

// ---------------- K3: final loss (cnt from memlab histogram, int4 scan) ----------------
__global__ void finalize_kernel(const float* __restrict__ rowS, const float* __restrict__ rowP,
                                const int* __restrict__ memlab, float* __restrict__ out) {
    const int t = threadIdx.x;
    __shared__ int hist[NCLS];
    __shared__ float rs[4], rn[4];
    if (t < NCLS) hist[t] = 0;
    __syncthreads();
    for (int i4 = t; i4 < NM / 4; i4 += 256) {     // 5000 int4s, 20 iterations
        const int4 v = ((const int4*)memlab)[i4];
        atomicAdd(&hist[v.x], 1);
        atomicAdd(&hist[v.y], 1);
        atomicAdd(&hist[v.z], 1);
        atomicAdd(&hist[v.w], 1);
    }
    __syncthreads();
    float sum = 0.f, nval = 0.f;
    for (int n = t; n < NA; n += 256) {
        const float cnt  = (float)(KPC - 1 + hist[(n * 5243) >> 19]);
        const float logS = logf(rowS[n] + 1e-12f);
        const float mean = (rowP[n] - cnt * logS) / fmaxf(cnt, 1.0f);
        if (cnt > 0.f) { sum += mean; nval += 1.f; }
    }
    for (int o = 32; o; o >>= 1) {
        sum  += __shfl_xor(sum, o, 64);
        nval += __shfl_xor(nval, o, 64);
    }
    if ((t & 63) == 0) { rs[t >> 6] = sum; rn[t >> 6] = nval; }
    __syncthreads();
    if (t == 0) {
        const float s  = rs[0] + rs[1] + rs[2] + rs[3];
        const float nv = rn[0] + rn[1] + rn[2] + rn[3];
        out[0] = -(0.1f / 0.07f) * (s / fmaxf(nv, 1.f));
    }
}

extern "C" void kernel_launch(void* const* d_in, const int* in_sizes, int n_in,
                              void* d_out, int out_size, void* d_ws, size_t ws_size,
                              hipStream_t stream) {
    const float* pixel  = (const float*)d_in[0];   // [8,256,128,128]
    const int*   labels = (const int*)d_in[1];     // [8,128,128]
    const float* mem    = (const float*)d_in[2];   // [20000,256]
    const int*   memlab = (const int*)d_in[3];     // [20000]
    char* ws = (char*)d_ws;
    float* rowS = (float*)(ws + WS_ROWS);
    float* rowP = (float*)(ws + WS_ROWP);
    int*   clab = (int*)(ws + WS_CLAB);
    short* Ct2  = (short*)(ws + WS_CT2);
    float* out  = (float*)d_out;

    prep_kernel<<<dim3(K1_GRID), dim3(256), 0, stream>>>(
        pixel, labels, mem, memlab, clab, Ct2, rowS, rowP);
    mfma_gemm_kernel<<<dim3(NTILES), dim3(256), 0, stream>>>(Ct2, clab, rowS, rowP);
    finalize_kernel<<<dim3(1), dim3(256), 0, stream>>>(rowS, rowP, memlab, out);
}